// Round 10
// baseline (369.200 us; speedup 1.0000x reference)
//
#include <hip/hip_runtime.h>
#include <hip/hip_cooperative_groups.h>

namespace cg = cooperative_groups;

#define D 128
#define KOUT 100
#define CHUNK 4096   // edges per pass-1 block

typedef __attribute__((ext_vector_type(8))) short short8;
typedef __attribute__((ext_vector_type(4))) float floatx4;

// ---------------- bf16 pack/unpack helpers ----------------
__device__ inline float bf_lo(unsigned int u) { return __uint_as_float(u << 16); }
__device__ inline float bf_hi(unsigned int u) { return __uint_as_float(u & 0xFFFF0000u); }

__device__ inline unsigned int bf_round(float a) {      // f32 -> bf16 bits (RNE)
    unsigned int ua = __float_as_uint(a);
    return (ua + 0x7FFFu + ((ua >> 16) & 1u)) >> 16;
}
__device__ inline unsigned int pack_bf(float a, float b) {
    return bf_round(a) | (bf_round(b) << 16);
}

// ---------------- Cooperative prologue ----------------
// phase 0: weight prep (blocks 0..191), bcur zero + rowptr sentinel (192),
//          zero rows + bpad (193)
// phase 1: bucket radix partition (blocks < nbP1)
// phase 2: per-bucket deg/dinv/rowptr + CSR scatter (blocks < nbuck)
// packed record: bits[23:0]=src, bits[31:24]=dst&255; bucket = dst>>8

__launch_bounds__(256)
__global__ void csr_coop_kernel(const int* __restrict__ ei, int E, int nbuck, int cap, int nbP1,
                                const float* __restrict__ W1, const float* __restrict__ W2,
                                const float* __restrict__ Wa, const float* __restrict__ ba,
                                unsigned short* __restrict__ Wf1, unsigned short* __restrict__ Wf2,
                                unsigned short* __restrict__ WfA, float* __restrict__ bpad,
                                int* __restrict__ bcur,
                                unsigned int* __restrict__ zrowA, unsigned int* __restrict__ zrowB,
                                unsigned int* __restrict__ bdata, float* __restrict__ dinv,
                                int* __restrict__ rowptr, int* __restrict__ csr, int n) {
    __shared__ int hist[256];
    __shared__ int sc[256];
    __shared__ int pfx[256];
    __shared__ int cur[256];
    __shared__ int gbase[256];
    __shared__ unsigned int lbuf[CHUNK];      // 16 KB
    __shared__ unsigned char bkt[CHUNK];      // 4 KB
    __shared__ int bbase;

    cg::grid_group grid = cg::this_grid();
    int bid = blockIdx.x, tid = threadIdx.x;

    // ---- phase 0 ----
    if (bid < 192) {
        int idx = bid * 256 + tid;            // < 49152 = 3*16384
        int m = idx / 16384;
        int e = idx & 16383;
        int j = e & 7, lane = (e >> 3) & 63, ct = (e >> 9) & 7, kt = e >> 12;
        int k = kt * 32 + (lane >> 4) * 8 + j;
        int col = ct * 16 + (lane & 15);
        float val;
        unsigned short* dst;
        if (m == 0)      { val = W1[k * 128 + col]; dst = Wf1; }
        else if (m == 1) { val = W2[k * 128 + col]; dst = Wf2; }
        else             { val = (col < KOUT) ? Wa[k * KOUT + col] : 0.f; dst = WfA; }
        dst[e] = (unsigned short)bf_round(val);
    } else if (bid == 192) {
        bcur[tid] = 0;
        if (tid == 0) rowptr[n] = E;          // sentinel
    } else if (bid == 193) {
        if (tid < 64) { zrowA[tid] = 0u; zrowB[tid] = 0u; }
        if (tid < 128) bpad[tid] = (tid < KOUT) ? ba[tid] : 0.f;
    }
    grid.sync();

    // ---- phase 1: bucket partition ----
    if (bid < nbP1) {
        int base = bid * CHUNK;
        int cnt = E - base; if (cnt > CHUNK) cnt = CHUNK;

        hist[tid] = 0;
        __syncthreads();

        int src[CHUNK / 256];
        int dst[CHUNK / 256];
#pragma unroll
        for (int q = 0; q < CHUNK / 256; q++) {
            int li = tid + q * 256;
            if (li < cnt) {
                src[q] = ei[base + li];
                dst[q] = ei[E + base + li];
                atomicAdd(&hist[dst[q] >> 8], 1);
            }
        }
        __syncthreads();

        int v = hist[tid];
        sc[tid] = v;
        __syncthreads();
        for (int off = 1; off < 256; off <<= 1) {
            int t = (tid >= off) ? sc[tid - off] : 0;
            __syncthreads();
            sc[tid] += t;
            __syncthreads();
        }
        int excl = sc[tid] - v;
        pfx[tid] = excl;
        cur[tid] = excl;
        gbase[tid] = 0;
        if (tid < nbuck && v > 0) gbase[tid] = atomicAdd(&bcur[tid], v);
        __syncthreads();

#pragma unroll
        for (int q = 0; q < CHUNK / 256; q++) {
            int li = tid + q * 256;
            if (li < cnt) {
                int b = dst[q] >> 8;
                int p = atomicAdd(&cur[b], 1);
                lbuf[p] = (unsigned int)src[q] | ((unsigned int)(dst[q] & 255) << 24);
                bkt[p] = (unsigned char)b;
            }
        }
        __syncthreads();

        for (int p = tid; p < cnt; p += 256) {
            int b = bkt[p];
            bdata[(size_t)b * cap + gbase[b] + (p - pfx[b])] = lbuf[p];
        }
    }
    grid.sync();

    // ---- phase 2: per-bucket build ----
    if (bid < nbuck) {
        int b = bid;
        if (tid == 0) bbase = 0;
        hist[tid] = 0;          // reuse hist as per-node counts
        __syncthreads();

        int part = 0;
        for (int t = tid; t < b; t += 256) part += bcur[t];
#pragma unroll
        for (int off = 32; off > 0; off >>= 1) part += __shfl_down(part, off);
        if ((tid & 63) == 0 && part != 0) atomicAdd(&bbase, part);

        int cnt = bcur[b];
        const unsigned int* p = bdata + (size_t)b * cap;
        for (int e = tid; e < cnt; e += 256) atomicAdd(&hist[p[e] >> 24], 1);
        __syncthreads();

        int v = hist[tid];
        sc[tid] = v;
        __syncthreads();
        for (int off = 1; off < 256; off <<= 1) {
            int t = (tid >= off) ? sc[tid - off] : 0;
            __syncthreads();
            sc[tid] += t;
            __syncthreads();
        }
        int gstart = bbase + (sc[tid] - v);
        int node = b * 256 + tid;
        if (node < n) {
            dinv[node] = rsqrtf((float)(v + 1));
            rowptr[node] = gstart;
        }
        cur[tid] = gstart;
        __syncthreads();

        for (int e = tid; e < cnt; e += 256) {
            unsigned int u = p[e];
            int pos = atomicAdd(&cur[u >> 24], 1);
            csr[pos] = (int)(u & 0xFFFFFFu);
        }
    }
}

// ---------------- MFMA GEMM ----------------
// block 256 = 4 waves; tile 64 rows x 128 cols; wave w: rows w*16..+15.
// in_bf16: A-fragments read directly from packed-bf16 global rows.
// out_mode 1: packed-bf16 rows, each row scaled by oscale[row] if given (dinv prescale).
// out_mode 2: +bias, softmax over first KOUT cols, f32 [nrows, KOUT] output.

__launch_bounds__(256)
__global__ void gemm_mfma_kernel(const void* __restrict__ Xin, const unsigned short* __restrict__ Wf,
                                 const float* __restrict__ bias, const float* __restrict__ oscale,
                                 void* __restrict__ Y, int nrows, int in_bf16, int out_mode) {
    __shared__ float lds_f[64 * 130];                      // 33280 B
    unsigned short* lds_h = (unsigned short*)lds_f;
    unsigned int* lds_u = (unsigned int*)lds_f;

    int tid = threadIdx.x;
    int w = tid >> 6, lane = tid & 63;
    int quad = lane >> 4, m16 = lane & 15;
    int r0 = blockIdx.x * 64;

    if (!in_bf16) {
        int row = tid >> 2, cg_ = tid & 3;
        bool valid = (r0 + row) < nrows;
        const float4* Xr = (const float4*)Xin + (size_t)(r0 + row) * 32 + cg_ * 8;
#pragma unroll
        for (int j = 0; j < 8; j++) {
            float4 v = valid ? Xr[j] : make_float4(0.f, 0.f, 0.f, 0.f);
            int c = cg_ * 32 + j * 4;
            lds_u[row * 68 + (c >> 1)]     = pack_bf(v.x, v.y);
            lds_u[row * 68 + (c >> 1) + 1] = pack_bf(v.z, v.w);
        }
        __syncthreads();
    }

    floatx4 acc[8];
#pragma unroll
    for (int ct = 0; ct < 8; ct++) acc[ct] = (floatx4){0.f, 0.f, 0.f, 0.f};

    int arow = r0 + w * 16 + m16;
    if (arow > nrows - 1) arow = nrows - 1;
    const unsigned int* Xb = (const unsigned int*)Xin;

    const short8* Wf8 = (const short8*)Wf;
#pragma unroll
    for (int kt = 0; kt < 4; kt++) {
        short8 a;
        if (in_bf16) {
            a = *(const short8*)(Xb + (size_t)arow * 64 + kt * 16 + quad * 4);
        } else {
            a = *(const short8*)(lds_h + (w * 16 + m16) * 136 + kt * 32 + quad * 8);
        }
#pragma unroll
        for (int ct = 0; ct < 8; ct++) {
            short8 b = Wf8[(kt * 8 + ct) * 64 + lane];
            acc[ct] = __builtin_amdgcn_mfma_f32_16x16x32_bf16(a, b, acc[ct], 0, 0, 0);
        }
    }

    if (out_mode == 1) {
        __syncthreads();   // reuse LDS as f32 out staging [64][130]
#pragma unroll
        for (int ct = 0; ct < 8; ct++) {
#pragma unroll
            for (int r = 0; r < 4; r++) {
                int rl = w * 16 + quad * 4 + r;
                lds_f[rl * 130 + ct * 16 + m16] = acc[ct][r];
            }
        }
        __syncthreads();
        unsigned int* Yb = (unsigned int*)Y;
        for (int r = 0; r < 16; r++) {
            int row = r0 + w * 16 + r;
            if (row < nrows) {
                float sc = oscale ? oscale[row] : 1.f;
                float lo = lds_f[(w * 16 + r) * 130 + 2 * lane] * sc;
                float hi = lds_f[(w * 16 + r) * 130 + 2 * lane + 1] * sc;
                Yb[(size_t)row * 64 + lane] = pack_bf(lo, hi);
            }
        }
    } else {
        // out_mode 2: bias + softmax over cols < KOUT, f32 output [nrows, KOUT]
        float bb[8];
#pragma unroll
        for (int ct = 0; ct < 8; ct++) bb[ct] = bias[ct * 16 + m16];
        float* Yf = (float*)Y;
#pragma unroll
        for (int r = 0; r < 4; r++) {
            int row = r0 + w * 16 + quad * 4 + r;
            float vv[8];
            float mx = -1e30f;
#pragma unroll
            for (int ct = 0; ct < 8; ct++) {
                int col = ct * 16 + m16;
                vv[ct] = (col < KOUT) ? acc[ct][r] + bb[ct] : -1e30f;
                mx = fmaxf(mx, vv[ct]);
            }
#pragma unroll
            for (int off = 1; off < 16; off <<= 1) mx = fmaxf(mx, __shfl_xor(mx, off));
            float se = 0.f;
#pragma unroll
            for (int ct = 0; ct < 8; ct++) {
                vv[ct] = (vv[ct] > -1e29f) ? __expf(vv[ct] - mx) : 0.f;
                se += vv[ct];
            }
#pragma unroll
            for (int off = 1; off < 16; off <<= 1) se += __shfl_xor(se, off);
            float inv = 1.f / se;
            if (row < nrows) {
#pragma unroll
                for (int ct = 0; ct < 8; ct++) {
                    int col = ct * 16 + m16;
                    if (col < KOUT) Yf[(size_t)row * KOUT + col] = vv[ct] * inv;
                }
            }
        }
    }
}

// ---------------- Aggregate (prescaled rows): Ob[i] = bf16( di*(Σ Hb'[src] + Hb'[i]) + b )
// Hb' rows already scaled by dinv[src] (GEMM epilogue). No per-edge weight.
// one wave per node; 4 groups of 16 lanes, group = 1 edge, lane = uint4 (8 feats).
// software-pipelined: next iteration's indices load while current gathers are in flight.
// masked tail points at zero-row index n. cnt from rowptr pair (sentinel rowptr[n]=E).

__launch_bounds__(256)
__global__ void aggregate_kernel(const uint4* __restrict__ Hb4, const int* __restrict__ csr,
                                 const int* __restrict__ rowptr,
                                 const float* __restrict__ dinv, const float* __restrict__ bias,
                                 unsigned int* __restrict__ Ob, int n, int do_relu) {
    int wid = threadIdx.x >> 6, lane = threadIdx.x & 63;
    int g = lane >> 4, c = lane & 15;
    int i = blockIdx.x * 4 + wid;
    if (i >= n) return;

    float di = dinv[i];
    int start = rowptr[i];
    int cnt = rowptr[i + 1] - start;
    const int* cp = csr + start;

    float acc[8];
    {   // self term (group 0 only)
        uint4 sv = Hb4[(size_t)i * 16 + c];
        unsigned int su[4] = {sv.x, sv.y, sv.z, sv.w};
        if (g != 0) { su[0] = su[1] = su[2] = su[3] = 0u; }
#pragma unroll
        for (int t = 0; t < 4; t++) {
            acc[2 * t]     = bf_lo(su[t]);
            acc[2 * t + 1] = bf_hi(su[t]);
        }
    }

    int s[4];
#pragma unroll
    for (int u = 0; u < 4; u++) {
        int idx = u * 4 + g;
        s[u] = (idx < cnt) ? cp[idx] : n;          // n = zero row
    }
    for (int e = 0; e < cnt; e += 16) {
        uint4 v[4];
#pragma unroll
        for (int u = 0; u < 4; u++) v[u] = Hb4[(size_t)s[u] * 16 + c];
        int ns[4];
#pragma unroll
        for (int u = 0; u < 4; u++) {
            int idx = e + 16 + u * 4 + g;
            ns[u] = (idx < cnt) ? cp[idx] : n;
        }
#pragma unroll
        for (int u = 0; u < 4; u++) {
            unsigned int uu[4] = {v[u].x, v[u].y, v[u].z, v[u].w};
#pragma unroll
            for (int t = 0; t < 4; t++) {
                acc[2 * t]     += bf_lo(uu[t]);
                acc[2 * t + 1] += bf_hi(uu[t]);
            }
        }
#pragma unroll
        for (int u = 0; u < 4; u++) s[u] = ns[u];
    }

    // butterfly across the 4 groups (lane bits 4,5)
#pragma unroll
    for (int j = 0; j < 8; j++) {
        acc[j] += __shfl_xor(acc[j], 16);
        acc[j] += __shfl_xor(acc[j], 32);
    }

    // lane (g,c) writes feature pair p = c*4+g (feats 8c+2g, 8c+2g+1)
    float2 bb = ((const float2*)bias)[c * 4 + g];
    float fx = acc[g * 2]     * di + bb.x;
    float fy = acc[g * 2 + 1] * di + bb.y;
    if (do_relu) { fx = fmaxf(fx, 0.f); fy = fmaxf(fy, 0.f); }
    Ob[(size_t)i * 64 + c * 4 + g] = pack_bf(fx, fy);
}

// ---------------- launch ----------------

extern "C" void kernel_launch(void* const* d_in, const int* in_sizes, int n_in,
                              void* d_out, int out_size, void* d_ws, size_t ws_size,
                              hipStream_t stream) {
    const float* x  = (const float*)d_in[0];
    const int*   ei = (const int*)d_in[1];     // [2,E] int32
    const float* W1 = (const float*)d_in[2];
    const float* b1 = (const float*)d_in[3];
    const float* W2 = (const float*)d_in[4];
    const float* b2 = (const float*)d_in[5];
    const float* Wa = (const float*)d_in[6];
    const float* ba = (const float*)d_in[7];
    float* out = (float*)d_out;

    int N = in_sizes[0] / D;
    int E = in_sizes[1] / 2;

    int nbuck = (N + 255) >> 8;                       // 196 for N=50000
    int cap = ((E / nbuck) + 2048 + 63) & ~63;

    char* w = (char*)d_ws;
    size_t off = 0;
    auto carve = [&](size_t bytes) -> void* {
        void* p = w + off;
        off = (off + bytes + 255) & ~(size_t)255;
        return p;
    };
    float* dinv   = (float*)carve((size_t)N * 4);
    int*   rowptr = (int*)carve((size_t)(N + 1) * 4);
    int*   bcur   = (int*)carve(256 * 4);
    unsigned int* bdata = (unsigned int*)carve((size_t)nbuck * cap * 4);
    int*   csr    = (int*)carve((size_t)E * 4);
    unsigned short* Wf1 = (unsigned short*)carve(16384 * 2);
    unsigned short* Wf2 = (unsigned short*)carve(16384 * 2);
    unsigned short* WfA = (unsigned short*)carve(16384 * 2);
    float* bpad   = (float*)carve(512);
    unsigned int* HbA = (unsigned int*)carve((size_t)(N + 1) * 64 * 4);  // +1 zero row
    unsigned int* HbB = (unsigned int*)carve((size_t)(N + 1) * 64 * 4);
    (void)ws_size; (void)n_in; (void)out_size;

    int nbNode4 = (N + 3) / 4;
    int nbGemm = (N + 63) / 64;
    int nbP1 = (E + CHUNK - 1) / CHUNK;

    int ngrid = nbP1;
    if (ngrid < nbuck) ngrid = nbuck;
    if (ngrid < 194) ngrid = 194;

    unsigned int* zrowA = HbA + (size_t)N * 64;
    unsigned int* zrowB = HbB + (size_t)N * 64;

    void* cargs[] = {
        (void*)&ei, (void*)&E, (void*)&nbuck, (void*)&cap, (void*)&nbP1,
        (void*)&W1, (void*)&W2, (void*)&Wa, (void*)&ba,
        (void*)&Wf1, (void*)&Wf2, (void*)&WfA, (void*)&bpad,
        (void*)&bcur, (void*)&zrowA, (void*)&zrowB,
        (void*)&bdata, (void*)&dinv, (void*)&rowptr, (void*)&csr, (void*)&N
    };
    (void)hipLaunchCooperativeKernel((void*)csr_coop_kernel, dim3(ngrid), dim3(256),
                                     cargs, 0, stream);

    // layer 1 (gemm writes bf16(h*dinv) rows)
    gemm_mfma_kernel<<<nbGemm, 256, 0, stream>>>(x, Wf1, nullptr, dinv, HbA, N, 0, 1);
    aggregate_kernel<<<nbNode4, 256, 0, stream>>>((const uint4*)HbA, csr, rowptr, dinv, b1, HbB, N, 1);
    // layer 2
    gemm_mfma_kernel<<<nbGemm, 256, 0, stream>>>(HbB, Wf2, nullptr, dinv, HbA, N, 1, 1);
    aggregate_kernel<<<nbNode4, 256, 0, stream>>>((const uint4*)HbA, csr, rowptr, dinv, b2, HbB, N, 0);
    // attention + fused softmax -> out
    gemm_mfma_kernel<<<nbGemm, 256, 0, stream>>>(HbB, WfA, bpad, nullptr, out, N, 1, 2);
}

// Round 11
// 264.651 us; speedup vs baseline: 1.3950x; 1.3950x over previous
//
#include <hip/hip_runtime.h>

#define D 128
#define KOUT 100
#define CHUNK 4096   // edges per pass-1 block

typedef __attribute__((ext_vector_type(8))) short short8;
typedef __attribute__((ext_vector_type(4))) float floatx4;

// ---------------- bf16 pack/unpack helpers ----------------
__device__ inline float bf_lo(unsigned int u) { return __uint_as_float(u << 16); }
__device__ inline float bf_hi(unsigned int u) { return __uint_as_float(u & 0xFFFF0000u); }

__device__ inline unsigned int bf_round(float a) {      // f32 -> bf16 bits (RNE)
    unsigned int ua = __float_as_uint(a);
    return (ua + 0x7FFFu + ((ua >> 16) & 1u)) >> 16;
}
__device__ inline unsigned int pack_bf(float a, float b) {
    return bf_round(a) | (bf_round(b) << 16);
}

// ---------------- CSR build pass 1: bucket radix partition ----------------
// bucket = dst >> 8; packed record: bits[23:0]=src, bits[31:24]=dst&255

__launch_bounds__(256)
__global__ void bucket_pass1(const int* __restrict__ ei, int E, int nbuck, int cap,
                             int* __restrict__ bcur, unsigned int* __restrict__ bdata) {
    __shared__ int hist[256];
    __shared__ int sc[256];
    __shared__ int pfx[256];
    __shared__ int cur[256];
    __shared__ int gbase[256];
    __shared__ unsigned int lbuf[CHUNK];      // 16 KB
    __shared__ unsigned char bkt[CHUNK];      // 4 KB

    int tid = threadIdx.x;
    int base = blockIdx.x * CHUNK;
    int cnt = E - base; if (cnt > CHUNK) cnt = CHUNK;

    hist[tid] = 0;
    __syncthreads();

    int src[CHUNK / 256];
    int dst[CHUNK / 256];
#pragma unroll
    for (int q = 0; q < CHUNK / 256; q++) {
        int li = tid + q * 256;
        if (li < cnt) {
            src[q] = ei[base + li];
            dst[q] = ei[E + base + li];
            atomicAdd(&hist[dst[q] >> 8], 1);
        }
    }
    __syncthreads();

    int v = hist[tid];
    sc[tid] = v;
    __syncthreads();
    for (int off = 1; off < 256; off <<= 1) {
        int t = (tid >= off) ? sc[tid - off] : 0;
        __syncthreads();
        sc[tid] += t;
        __syncthreads();
    }
    int excl = sc[tid] - v;
    pfx[tid] = excl;
    cur[tid] = excl;
    gbase[tid] = 0;
    if (tid < nbuck && v > 0) gbase[tid] = atomicAdd(&bcur[tid], v);
    __syncthreads();

#pragma unroll
    for (int q = 0; q < CHUNK / 256; q++) {
        int li = tid + q * 256;
        if (li < cnt) {
            int b = dst[q] >> 8;
            int p = atomicAdd(&cur[b], 1);
            lbuf[p] = (unsigned int)src[q] | ((unsigned int)(dst[q] & 255) << 24);
            bkt[p] = (unsigned char)b;
        }
    }
    __syncthreads();

    for (int p = tid; p < cnt; p += 256) {
        int b = bkt[p];
        bdata[(size_t)b * cap + gbase[b] + (p - pfx[b])] = lbuf[p];
    }
}

// ---------------- CSR build pass 2 (fused): dinv + rowptr + scatter ----------------
// one block per bucket; bdata read twice (2nd read L2-hot).

__launch_bounds__(256)
__global__ void bucket_build(const unsigned int* __restrict__ bdata, const int* __restrict__ bcur,
                             int cap, float* __restrict__ dinv,
                             int* __restrict__ rowptr, int* __restrict__ csr, int n, int nbuck) {
    __shared__ int cnts[256];
    __shared__ int sc[256];
    __shared__ int cur[256];
    __shared__ int bbase;

    int b = blockIdx.x, tid = threadIdx.x;
    if (tid == 0) bbase = 0;
    cnts[tid] = 0;
    __syncthreads();

    // sum of bucket counts before b
    int part = 0;
    for (int t = tid; t < b; t += 256) part += bcur[t];
#pragma unroll
    for (int off = 32; off > 0; off >>= 1) part += __shfl_down(part, off);
    if ((tid & 63) == 0 && part != 0) atomicAdd(&bbase, part);

    int cnt = bcur[b];
    const unsigned int* p = bdata + (size_t)b * cap;
    for (int e = tid; e < cnt; e += 256) atomicAdd(&cnts[p[e] >> 24], 1);
    __syncthreads();

    int v = cnts[tid];
    sc[tid] = v;
    __syncthreads();
    for (int off = 1; off < 256; off <<= 1) {
        int t = (tid >= off) ? sc[tid - off] : 0;
        __syncthreads();
        sc[tid] += t;
        __syncthreads();
    }
    int gstart = bbase + (sc[tid] - v);
    int node = b * 256 + tid;
    if (node < n) {
        dinv[node] = rsqrtf((float)(v + 1));
        rowptr[node] = gstart;
    }
    cur[tid] = gstart;
    __syncthreads();

    for (int e = tid; e < cnt; e += 256) {
        unsigned int u = p[e];
        int pos = atomicAdd(&cur[u >> 24], 1);
        csr[pos] = (int)(u & 0xFFFFFFu);
    }
}

// ---------------- Weight prep + bcur zero + Hb zero-rows + rowptr sentinel ----------------
// Wfrag[(kt*8+ct)*64 + lane][j] = W[kt*32 + (lane>>4)*8 + j][ct*16 + (lane&15)]

__global__ void prep_frag_kernel(const float* __restrict__ W1, const float* __restrict__ W2,
                                 const float* __restrict__ Wa, const float* __restrict__ ba,
                                 unsigned short* __restrict__ Wf1, unsigned short* __restrict__ Wf2,
                                 unsigned short* __restrict__ WfA, float* __restrict__ bpad,
                                 int* __restrict__ bcur, int* __restrict__ rowptr,
                                 unsigned int* __restrict__ zrowA, unsigned int* __restrict__ zrowB,
                                 int n, int E) {
    int idx = blockIdx.x * blockDim.x + threadIdx.x;
    if (idx < 3 * 16384) {
        int m = idx / 16384;
        int e = idx & 16383;
        int j = e & 7, lane = (e >> 3) & 63, ct = (e >> 9) & 7, kt = e >> 12;
        int k = kt * 32 + (lane >> 4) * 8 + j;
        int col = ct * 16 + (lane & 15);
        float val;
        unsigned short* dst;
        if (m == 0)      { val = W1[k * 128 + col]; dst = Wf1; }
        else if (m == 1) { val = W2[k * 128 + col]; dst = Wf2; }
        else             { val = (col < KOUT) ? Wa[k * KOUT + col] : 0.f; dst = WfA; }
        dst[e] = (unsigned short)bf_round(val);
    }
    if (idx < 128) bpad[idx] = (idx < KOUT) ? ba[idx] : 0.f;
    if (idx < 256) bcur[idx] = 0;
    if (idx < 64) { zrowA[idx] = 0u; zrowB[idx] = 0u; }
    if (idx == 256) rowptr[n] = E;   // sentinel
}

// ---------------- MFMA GEMM ----------------
// block 256 = 4 waves; tile 64 rows x 128 cols; wave w: rows w*16..+15.
// in_bf16: A-fragments read directly from packed-bf16 global rows.
// out_mode 1: packed-bf16 rows, each row scaled by oscale[row] if given (dinv prescale).
// out_mode 2: +bias, softmax over first KOUT cols, f32 [nrows, KOUT] output.

__launch_bounds__(256)
__global__ void gemm_mfma_kernel(const void* __restrict__ Xin, const unsigned short* __restrict__ Wf,
                                 const float* __restrict__ bias, const float* __restrict__ oscale,
                                 void* __restrict__ Y, int nrows, int in_bf16, int out_mode) {
    __shared__ float lds_f[64 * 130];                      // 33280 B
    unsigned short* lds_h = (unsigned short*)lds_f;
    unsigned int* lds_u = (unsigned int*)lds_f;

    int tid = threadIdx.x;
    int w = tid >> 6, lane = tid & 63;
    int quad = lane >> 4, m16 = lane & 15;
    int r0 = blockIdx.x * 64;

    if (!in_bf16) {
        int row = tid >> 2, cg_ = tid & 3;
        bool valid = (r0 + row) < nrows;
        const float4* Xr = (const float4*)Xin + (size_t)(r0 + row) * 32 + cg_ * 8;
#pragma unroll
        for (int j = 0; j < 8; j++) {
            float4 v = valid ? Xr[j] : make_float4(0.f, 0.f, 0.f, 0.f);
            int c = cg_ * 32 + j * 4;
            lds_u[row * 68 + (c >> 1)]     = pack_bf(v.x, v.y);
            lds_u[row * 68 + (c >> 1) + 1] = pack_bf(v.z, v.w);
        }
        __syncthreads();
    }

    floatx4 acc[8];
#pragma unroll
    for (int ct = 0; ct < 8; ct++) acc[ct] = (floatx4){0.f, 0.f, 0.f, 0.f};

    int arow = r0 + w * 16 + m16;
    if (arow > nrows - 1) arow = nrows - 1;
    const unsigned int* Xb = (const unsigned int*)Xin;

    const short8* Wf8 = (const short8*)Wf;
#pragma unroll
    for (int kt = 0; kt < 4; kt++) {
        short8 a;
        if (in_bf16) {
            a = *(const short8*)(Xb + (size_t)arow * 64 + kt * 16 + quad * 4);
        } else {
            a = *(const short8*)(lds_h + (w * 16 + m16) * 136 + kt * 32 + quad * 8);
        }
#pragma unroll
        for (int ct = 0; ct < 8; ct++) {
            short8 b = Wf8[(kt * 8 + ct) * 64 + lane];
            acc[ct] = __builtin_amdgcn_mfma_f32_16x16x32_bf16(a, b, acc[ct], 0, 0, 0);
        }
    }

    if (out_mode == 1) {
        __syncthreads();   // reuse LDS as f32 out staging [64][130]
#pragma unroll
        for (int ct = 0; ct < 8; ct++) {
#pragma unroll
            for (int r = 0; r < 4; r++) {
                int rl = w * 16 + quad * 4 + r;
                lds_f[rl * 130 + ct * 16 + m16] = acc[ct][r];
            }
        }
        __syncthreads();
        unsigned int* Yb = (unsigned int*)Y;
        for (int r = 0; r < 16; r++) {
            int row = r0 + w * 16 + r;
            if (row < nrows) {
                float sc = oscale ? oscale[row] : 1.f;
                float lo = lds_f[(w * 16 + r) * 130 + 2 * lane] * sc;
                float hi = lds_f[(w * 16 + r) * 130 + 2 * lane + 1] * sc;
                Yb[(size_t)row * 64 + lane] = pack_bf(lo, hi);
            }
        }
    } else {
        // out_mode 2: bias + softmax over cols < KOUT, f32 output [nrows, KOUT]
        float bb[8];
#pragma unroll
        for (int ct = 0; ct < 8; ct++) bb[ct] = bias[ct * 16 + m16];
        float* Yf = (float*)Y;
#pragma unroll
        for (int r = 0; r < 4; r++) {
            int row = r0 + w * 16 + quad * 4 + r;
            float vv[8];
            float mx = -1e30f;
#pragma unroll
            for (int ct = 0; ct < 8; ct++) {
                int col = ct * 16 + m16;
                vv[ct] = (col < KOUT) ? acc[ct][r] + bb[ct] : -1e30f;
                mx = fmaxf(mx, vv[ct]);
            }
#pragma unroll
            for (int off = 1; off < 16; off <<= 1) mx = fmaxf(mx, __shfl_xor(mx, off));
            float se = 0.f;
#pragma unroll
            for (int ct = 0; ct < 8; ct++) {
                vv[ct] = (vv[ct] > -1e29f) ? __expf(vv[ct] - mx) : 0.f;
                se += vv[ct];
            }
#pragma unroll
            for (int off = 1; off < 16; off <<= 1) se += __shfl_xor(se, off);
            float inv = 1.f / se;
            if (row < nrows) {
#pragma unroll
                for (int ct = 0; ct < 8; ct++) {
                    int col = ct * 16 + m16;
                    if (col < KOUT) Yf[(size_t)row * KOUT + col] = vv[ct] * inv;
                }
            }
        }
    }
}

// ---------------- Aggregate (prescaled rows): Ob[i] = bf16( di*(Σ Hb'[src] + Hb'[i]) + b )
// Hb' rows already scaled by dinv[src] (GEMM epilogue). No per-edge weight.
// one wave per node; 4 groups of 16 lanes, group = 1 edge, lane = uint4 (8 feats).
// software-pipelined: next iteration's indices load while current gathers are in flight.
// masked tail points at zero-row index n. cnt from rowptr pair (sentinel rowptr[n]=E).

__launch_bounds__(256)
__global__ void aggregate_kernel(const uint4* __restrict__ Hb4, const int* __restrict__ csr,
                                 const int* __restrict__ rowptr,
                                 const float* __restrict__ dinv, const float* __restrict__ bias,
                                 unsigned int* __restrict__ Ob, int n, int do_relu) {
    int wid = threadIdx.x >> 6, lane = threadIdx.x & 63;
    int g = lane >> 4, c = lane & 15;
    int i = blockIdx.x * 4 + wid;
    if (i >= n) return;

    float di = dinv[i];
    int start = rowptr[i];
    int cnt = rowptr[i + 1] - start;
    const int* cp = csr + start;

    float acc[8];
    {   // self term (group 0 only)
        uint4 sv = Hb4[(size_t)i * 16 + c];
        unsigned int su[4] = {sv.x, sv.y, sv.z, sv.w};
        if (g != 0) { su[0] = su[1] = su[2] = su[3] = 0u; }
#pragma unroll
        for (int t = 0; t < 4; t++) {
            acc[2 * t]     = bf_lo(su[t]);
            acc[2 * t + 1] = bf_hi(su[t]);
        }
    }

    int s[4];
#pragma unroll
    for (int u = 0; u < 4; u++) {
        int idx = u * 4 + g;
        s[u] = (idx < cnt) ? cp[idx] : n;          // n = zero row
    }
    for (int e = 0; e < cnt; e += 16) {
        uint4 v[4];
#pragma unroll
        for (int u = 0; u < 4; u++) v[u] = Hb4[(size_t)s[u] * 16 + c];
        int ns[4];
#pragma unroll
        for (int u = 0; u < 4; u++) {
            int idx = e + 16 + u * 4 + g;
            ns[u] = (idx < cnt) ? cp[idx] : n;
        }
#pragma unroll
        for (int u = 0; u < 4; u++) {
            unsigned int uu[4] = {v[u].x, v[u].y, v[u].z, v[u].w};
#pragma unroll
            for (int t = 0; t < 4; t++) {
                acc[2 * t]     += bf_lo(uu[t]);
                acc[2 * t + 1] += bf_hi(uu[t]);
            }
        }
#pragma unroll
        for (int u = 0; u < 4; u++) s[u] = ns[u];
    }

    // butterfly across the 4 groups (lane bits 4,5)
#pragma unroll
    for (int j = 0; j < 8; j++) {
        acc[j] += __shfl_xor(acc[j], 16);
        acc[j] += __shfl_xor(acc[j], 32);
    }

    // lane (g,c) writes feature pair p = c*4+g (feats 8c+2g, 8c+2g+1)
    float2 bb = ((const float2*)bias)[c * 4 + g];
    float fx = acc[g * 2]     * di + bb.x;
    float fy = acc[g * 2 + 1] * di + bb.y;
    if (do_relu) { fx = fmaxf(fx, 0.f); fy = fmaxf(fy, 0.f); }
    Ob[(size_t)i * 64 + c * 4 + g] = pack_bf(fx, fy);
}

// ---------------- launch ----------------

extern "C" void kernel_launch(void* const* d_in, const int* in_sizes, int n_in,
                              void* d_out, int out_size, void* d_ws, size_t ws_size,
                              hipStream_t stream) {
    const float* x  = (const float*)d_in[0];
    const int*   ei = (const int*)d_in[1];     // [2,E] int32
    const float* W1 = (const float*)d_in[2];
    const float* b1 = (const float*)d_in[3];
    const float* W2 = (const float*)d_in[4];
    const float* b2 = (const float*)d_in[5];
    const float* Wa = (const float*)d_in[6];
    const float* ba = (const float*)d_in[7];
    float* out = (float*)d_out;

    int N = in_sizes[0] / D;
    int E = in_sizes[1] / 2;

    int nbuck = (N + 255) >> 8;                       // 196 for N=50000
    int cap = ((E / nbuck) + 2048 + 63) & ~63;

    char* w = (char*)d_ws;
    size_t off = 0;
    auto carve = [&](size_t bytes) -> void* {
        void* p = w + off;
        off = (off + bytes + 255) & ~(size_t)255;
        return p;
    };
    float* dinv   = (float*)carve((size_t)N * 4);
    int*   rowptr = (int*)carve((size_t)(N + 1) * 4);
    int*   bcur   = (int*)carve(256 * 4);
    unsigned int* bdata = (unsigned int*)carve((size_t)nbuck * cap * 4);
    int*   csr    = (int*)carve((size_t)E * 4);
    unsigned short* Wf1 = (unsigned short*)carve(16384 * 2);
    unsigned short* Wf2 = (unsigned short*)carve(16384 * 2);
    unsigned short* WfA = (unsigned short*)carve(16384 * 2);
    float* bpad   = (float*)carve(512);
    unsigned int* HbA = (unsigned int*)carve((size_t)(N + 1) * 64 * 4);  // +1 zero row
    unsigned int* HbB = (unsigned int*)carve((size_t)(N + 1) * 64 * 4);
    (void)ws_size; (void)n_in; (void)out_size;

    int nbNode4 = (N + 3) / 4;
    int nbGemm = (N + 63) / 64;
    int nbP1 = (E + CHUNK - 1) / CHUNK;

    prep_frag_kernel<<<192, 256, 0, stream>>>(W1, W2, Wa, ba, Wf1, Wf2, WfA, bpad,
                                              bcur, rowptr,
                                              HbA + (size_t)N * 64, HbB + (size_t)N * 64, N, E);
    bucket_pass1<<<nbP1, 256, 0, stream>>>(ei, E, nbuck, cap, bcur, bdata);
    bucket_build<<<nbuck, 256, 0, stream>>>(bdata, bcur, cap, dinv, rowptr, csr, N, nbuck);

    // layer 1 (gemm writes bf16(h*dinv) rows)
    gemm_mfma_kernel<<<nbGemm, 256, 0, stream>>>(x, Wf1, nullptr, dinv, HbA, N, 0, 1);
    aggregate_kernel<<<nbNode4, 256, 0, stream>>>((const uint4*)HbA, csr, rowptr, dinv, b1, HbB, N, 1);
    // layer 2
    gemm_mfma_kernel<<<nbGemm, 256, 0, stream>>>(HbB, Wf2, nullptr, dinv, HbA, N, 1, 1);
    aggregate_kernel<<<nbNode4, 256, 0, stream>>>((const uint4*)HbA, csr, rowptr, dinv, b2, HbB, N, 0);
    // attention + fused softmax -> out
    gemm_mfma_kernel<<<nbGemm, 256, 0, stream>>>(HbB, WfA, bpad, nullptr, out, N, 1, 2);
}